// Round 1
// baseline (9.574 us; speedup 1.0000x reference)
//
#include <hip/hip_runtime.h>
#include <hip/hip_bf16.h>

// Output L has shape (1,2,2,3) -> 12 float32 elements, row-major flat:
//   flat(i1,i2,i3) = i1*6 + i2*3 + i3
//   L[0,0,0,0] -> 0  = 1.0
//   L[0,1,1,1] -> 10 = cos(theta)
//   L[0,1,1,2] -> 11 = sin(theta)
//   all others = 0
__global__ void SO4LR_45157286150747_kernel(const float* __restrict__ theta,
                                            float* __restrict__ out) {
    int i = threadIdx.x;
    if (i < 12) {
        float t = theta[0];
        float v = 0.0f;
        if (i == 0)       v = 1.0f;
        else if (i == 10) v = __cosf(t) == __cosf(t) ? cosf(t) : 0.0f; // keep precise path
        else if (i == 11) v = sinf(t);
        out[i] = v;
    }
}

extern "C" void kernel_launch(void* const* d_in, const int* in_sizes, int n_in,
                              void* d_out, int out_size, void* d_ws, size_t ws_size,
                              hipStream_t stream) {
    const float* theta = (const float*)d_in[0];
    float* out = (float*)d_out;
    // One wave; lanes 0..11 each own one output element. All 12 elements are
    // written every call (harness poisons d_out once, never re-poisons).
    SO4LR_45157286150747_kernel<<<1, 64, 0, stream>>>(theta, out);
}